// Round 3
// baseline (410.645 us; speedup 1.0000x reference)
//
#include <hip/hip_runtime.h>

// AlignmentMatrix: out[b,i,j] = sum_d body[b,i,d]*w3[d]*pun[b,j,d]
//                             + dot(body[b,i,:],w1) + dot(pun[b,j,:],w2)
// B=64, L=1024, D=128, fp32 in/out.
//
// R5: attack read traffic, not scheduling.
//  - 256x256 output tile (1024 blocks): re-read factor 8 -> 4.
//  - XCD-chunked bijective block swizzle: each XCD owns whole batches ->
//    per-XCD working set 2 MB < 4 MB L2, re-reads are local L2 hits.
//  - dbuf LDS (128 KB) + global_load_lds(16B) + counted vmcnt(8) (T3/T4).
//  - swapped MFMA operands (A=pun, B=body) -> float4 stores along j.
// prep pass (bf16 hi/lo split, w3 folded into body) unchanged from R3/R4.

#define LSEQ 1024
#define H2K  128

// ws layout:
//   ws[0      .. 65536)   s_body (fp32)
//   ws[65536  .. 131072)  s_pun  (fp32)
//   shorts at base=(short*)(ws+131072):
//     [0        ..  8388608)  body*w3  bf16 hi
//     [8388608  .. 16777216)  body*w3  bf16 lo
//     [16777216 .. 25165824)  pun      bf16 hi
//     [25165824 .. 33554432)  pun      bf16 lo

typedef __attribute__((ext_vector_type(8))) short bfrag;
typedef __attribute__((ext_vector_type(4))) float f32x4;

__device__ __forceinline__ short f2bf(float x) {
    unsigned u = __float_as_uint(x);
    unsigned r = (u + 0x7fff + ((u >> 16) & 1)) >> 16;   // RNE
    return (short)r;
}
__device__ __forceinline__ float bf2f(short s) {
    return __uint_as_float(((unsigned)(unsigned short)s) << 16);
}

__device__ __forceinline__ void ld16(void* lds, const void* g) {
    __builtin_amdgcn_global_load_lds(
        (const __attribute__((address_space(1))) void*)g,
        (__attribute__((address_space(3))) void*)lds, 16, 0, 0);
}

// --- pre-pass: one wave per row. fp32 rank-1 dot + bf16 hi/lo split write.
__global__ __launch_bounds__(256) void prep_kernel(
    const float* __restrict__ body, const float* __restrict__ pun,
    const float* __restrict__ w_u, float* __restrict__ ws)
{
    const int flag = blockIdx.y;                   // 0=body, 1=pun
    const int lane = threadIdx.x & 63;
    const int wv   = threadIdx.x >> 6;
    const size_t row = (size_t)blockIdx.x * 4 + wv;        // [0, B*LSEQ)

    const float* src = (flag ? pun : body) + row * H2K;
    const float2 v  = *(const float2*)(src + lane * 2);
    const float2 wm = *(const float2*)(w_u + flag * H2K + lane * 2);

    float p = v.x * wm.x + v.y * wm.y;
    p += __shfl_xor(p, 32);
    p += __shfl_xor(p, 16);
    p += __shfl_xor(p, 8);
    p += __shfl_xor(p, 4);
    p += __shfl_xor(p, 2);
    p += __shfl_xor(p, 1);
    if (lane == 0) ws[(size_t)flag * 65536 + row] = p;

    float cx = v.x, cy = v.y;
    if (!flag) {
        const float2 w3v = *(const float2*)(w_u + 2 * H2K + lane * 2);
        cx *= w3v.x; cy *= w3v.y;
    }
    const short h0 = f2bf(cx), h1 = f2bf(cy);
    const short l0 = f2bf(cx - bf2f(h0)), l1 = f2bf(cy - bf2f(h1));

    short* hb = (short*)(ws + 131072) + (size_t)flag * 16777216 + row * H2K + lane * 2;
    *(unsigned*)hb =
        ((unsigned)(unsigned short)h0) | ((unsigned)(unsigned short)h1 << 16);
    *(unsigned*)(hb + 8388608) =
        ((unsigned)(unsigned short)l0) | ((unsigned)(unsigned short)l1 << 16);
}

// --- main kernel: 256x256 tile / 512 threads, K chunked 4x32, dbuf LDS.
__global__ __launch_bounds__(512, 2) void align_mfma(
    const float* __restrict__ ws, float* __restrict__ out)
{
    // C = body (MFMA B operand), P = pun (MFMA A operand).
    // Per chunk per operand-half: 16 row-tiles x 64 lane-frags x 16 B = 16 KB.
    __shared__ __align__(16) short Ch[2][8192], Cl[2][8192];
    __shared__ __align__(16) short Ph[2][8192], Pl[2][8192];   // 128 KB total

    // XCD-chunked bijective swizzle: hardware xcd ~ blockIdx%8; give each
    // xcd a contiguous range of work-tiles (= whole batches).
    const int nwg = gridDim.x;                 // B*16, divisible by 8
    const int bid = blockIdx.x;
    const int tid = (bid & 7) * (nwg >> 3) + (bid >> 3);
    const int bb = tid >> 4;                   // batch
    const int ti = ((tid >> 2) & 3) * 256;     // body rows (output rows)
    const int tj = (tid & 3) * 256;            // pun rows  (output cols)

    const int t    = threadIdx.x;
    const int lane = t & 63;
    const int w    = t >> 6;                   // wave id 0..7

    // Staging: thread t owns lane-frags t and t+512 of each operand-half:
    //   frag f: tile=f>>6, l=f&63 -> row=(f>>6)*16+(l&15), k8=l>>4.
    //   LDS dest byte = f*16 (wave-uniform base + lane*16, both halves). OK.
    const int srow = w * 16 + (lane & 15);
    const int k8   = lane >> 4;
    const short* base = (const short*)(ws + 131072);
    const size_t crow = (size_t)(bb * LSEQ + ti + srow) * H2K + k8 * 8;
    const size_t prow = (size_t)(bb * LSEQ + tj + srow) * H2K + k8 * 8;
    const short* gCh = base + crow;
    const short* gCl = base + 8388608 + crow;
    const short* gPh = base + 16777216 + prow;
    const short* gPl = base + 25165824 + prow;
    const size_t R2 = (size_t)128 * H2K;       // +128 rows for second frag

#define STAGE(u, c) do {                                         \
        ld16(&Ch[u][t * 8],         gCh + (c) * 32);             \
        ld16(&Ch[u][(512 + t) * 8], gCh + R2 + (c) * 32);        \
        ld16(&Cl[u][t * 8],         gCl + (c) * 32);             \
        ld16(&Cl[u][(512 + t) * 8], gCl + R2 + (c) * 32);        \
        ld16(&Ph[u][t * 8],         gPh + (c) * 32);             \
        ld16(&Ph[u][(512 + t) * 8], gPh + R2 + (c) * 32);        \
        ld16(&Pl[u][t * 8],         gPl + (c) * 32);             \
        ld16(&Pl[u][(512 + t) * 8], gPl + R2 + (c) * 32);        \
    } while (0)

    // Wave work: 16 j-tiles x 16 i-tiles; wave w -> jg=w&1 (8 jt), ig=w>>1 (4 it).
    const int jg = w & 1;
    const int ig = w >> 1;
    f32x4 acc[8][4] = {};

    STAGE(0, 0);                               // prologue: chunk 0 -> buf 0

#pragma unroll
    for (int kt = 0; kt < 4; ++kt) {
        const int cur = kt & 1, nxt = cur ^ 1;

        if (kt < 3) STAGE(nxt, kt + 1);        // stays in flight across barrier
        __builtin_amdgcn_sched_barrier(0);
        if (kt < 3) asm volatile("s_waitcnt vmcnt(8)" ::: "memory");
        else        asm volatile("s_waitcnt vmcnt(0)" ::: "memory");
        __builtin_amdgcn_s_barrier();          // chunk kt landed for all waves

        // compute chunk kt: 96 MFMAs / wave
        bfrag ph[8], pl[8];
#pragma unroll
        for (int jj = 0; jj < 8; ++jj) {
            ph[jj] = *(const bfrag*)&Ph[cur][((jg * 8 + jj) * 64 + lane) * 8];
            pl[jj] = *(const bfrag*)&Pl[cur][((jg * 8 + jj) * 64 + lane) * 8];
        }
#pragma unroll
        for (int ii = 0; ii < 4; ++ii) {
            const bfrag ch = *(const bfrag*)&Ch[cur][((ig * 4 + ii) * 64 + lane) * 8];
            const bfrag cl = *(const bfrag*)&Cl[cur][((ig * 4 + ii) * 64 + lane) * 8];
#pragma unroll
            for (int jj = 0; jj < 8; ++jj) {
                acc[jj][ii] = __builtin_amdgcn_mfma_f32_16x16x32_bf16(ph[jj], ch, acc[jj][ii], 0, 0, 0);
                acc[jj][ii] = __builtin_amdgcn_mfma_f32_16x16x32_bf16(ph[jj], cl, acc[jj][ii], 0, 0, 0);
                acc[jj][ii] = __builtin_amdgcn_mfma_f32_16x16x32_bf16(pl[jj], ch, acc[jj][ii], 0, 0, 0);
            }
        }

        if (kt < 3) __builtin_amdgcn_s_barrier();  // protect buf before restage
        __builtin_amdgcn_sched_barrier(0);
    }
#undef STAGE

    // ---- epilogue: + s_body[i] + s_pun[j], float4 stores along j ----
    // D mapping (swapped): col j = tj + jt*16 + (lane>>4)*4 + reg; row i = ti + it*16 + (lane&15).
    const float* sbp = ws + (size_t)bb * LSEQ;
    const float* spp = ws + 65536 + (size_t)bb * LSEQ;
    const int qd = lane >> 4, ln = lane & 15;
#pragma unroll
    for (int jj = 0; jj < 8; ++jj) {
        const int j0 = tj + (jg * 8 + jj) * 16 + qd * 4;
        const float4 spv = *(const float4*)(spp + j0);
#pragma unroll
        for (int ii = 0; ii < 4; ++ii) {
            const int row = ti + (ig * 4 + ii) * 16 + ln;
            const float sb = sbp[row];
            const f32x4 a = acc[jj][ii];
            float4 r = { a[0] + sb + spv.x, a[1] + sb + spv.y,
                         a[2] + sb + spv.z, a[3] + sb + spv.w };
            *(float4*)&out[((size_t)bb * LSEQ + row) * LSEQ + j0] = r;
        }
    }
}

extern "C" void kernel_launch(void* const* d_in, const int* in_sizes, int n_in,
                              void* d_out, int out_size, void* d_ws, size_t ws_size,
                              hipStream_t stream) {
    const float* body = (const float*)d_in[1];
    const float* pun  = (const float*)d_in[2];
    const float* w_u  = (const float*)d_in[3];
    float* out = (float*)d_out;
    float* ws  = (float*)d_ws;
    const int B = in_sizes[1] / (LSEQ * H2K);

    dim3 g1((B * LSEQ) / 4, 2, 1);
    prep_kernel<<<g1, 256, 0, stream>>>(body, pun, w_u, ws);

    dim3 g2(B * 16, 1, 1);
    align_mfma<<<g2, 512, 0, stream>>>(ws, out);
}